// Round 12
// baseline (324.164 us; speedup 1.0000x reference)
//
#include <hip/hip_runtime.h>
#include <hip/hip_bf16.h>

constexpr int N = 10000;   // nodes
constexpr int D = 512;     // feature dim
constexpr int E = 160000;  // edges
constexpr int L = 3;       // layers
constexpr float EPS = 1e-5f;

typedef _Float16 half8 __attribute__((ext_vector_type(8)));
typedef _Float16 half2v __attribute__((ext_vector_type(2)));
typedef float floatx4 __attribute__((ext_vector_type(4)));

// async global->LDS, 16B per lane. LDS dest = wave-uniform base + lane*16.
// NOTE: padded LDS rows are impossible with this instruction (m104/m108);
// BK=64 rejected: stride-128B rows would be 16-way bank-aliased on ds_read_b128
// (current BK=32 stride-64B is at the 8-clock b128 structural floor).
__device__ __forceinline__ void glds16(const _Float16* g, _Float16* l) {
    __builtin_amdgcn_global_load_lds(
        (const __attribute__((address_space(1))) uint32_t*)(g),
        (__attribute__((address_space(3))) uint32_t*)(l),
        16, 0, 0);
}

// ---------------------------------------------------------------------------
// Mega setup: degrees + x fp32->f16 + column stats + W transpose. (r7 verbatim)
// ---------------------------------------------------------------------------
constexpr int DEG_BLOCKS  = (E + 255) / 256;   // 625
constexpr int CONV_BLOCKS = 100;               // 100 rows each
constexpr int TW_BLOCKS   = L * 256;           // 768 (32x32 tiles)
constexpr int MEGA_BLOCKS = DEG_BLOCKS + CONV_BLOCKS + TW_BLOCKS;

__global__ __launch_bounds__(256) void mega_setup(
    const int* __restrict__ src, const int* __restrict__ dst,
    const float* __restrict__ x, const float* __restrict__ W,
    int* __restrict__ out_deg, int* __restrict__ in_deg,
    _Float16* __restrict__ x16, float* __restrict__ stats0,
    _Float16* __restrict__ Wt) {
    __shared__ float tb[32][33];
    int bid = blockIdx.x;
    int tid = threadIdx.x;
    if (bid < DEG_BLOCKS) {
        int e = bid * 256 + tid;
        if (e < E) {
            atomicAdd(&out_deg[src[e]], 1);
            atomicAdd(&in_deg[dst[e]], 1);
        }
    } else if (bid < DEG_BLOCKS + CONV_BLOCKS) {
        int b = bid - DEG_BLOCKS;
        int r0 = b * 100;
        int r1 = r0 + 100; if (r1 > N) r1 = N;
        int c2 = tid * 2;
        float s0 = 0.f, s1 = 0.f, q0 = 0.f, q1 = 0.f;
        for (int r = r0; r < r1; ++r) {
            float2 v = *(const float2*)(x + (size_t)r * D + c2);
            s0 += v.x; q0 += v.x * v.x;
            s1 += v.y; q1 += v.y * v.y;
            half2v h; h[0] = (_Float16)v.x; h[1] = (_Float16)v.y;
            *(half2v*)(x16 + (size_t)r * D + c2) = h;
        }
        atomicAdd(&stats0[c2], s0);
        atomicAdd(&stats0[c2 + 1], s1);
        atomicAdd(&stats0[D + c2], q0);
        atomicAdd(&stats0[D + c2 + 1], q1);
    } else {
        int b = bid - DEG_BLOCKS - CONV_BLOCKS;  // 0..767
        int l = b >> 8;
        int t = b & 255;
        int k0 = (t >> 4) * 32, n0 = (t & 15) * 32;
        int tx = tid & 31, ty = tid >> 5;  // 32 x 8
        const float* Wl = W + (size_t)l * D * D;
        _Float16* Wtl = Wt + (size_t)l * D * D;
        for (int i = 0; i < 32; i += 8)
            tb[ty + i][tx] = Wl[(size_t)(k0 + ty + i) * D + n0 + tx];
        __syncthreads();
        for (int i = 0; i < 32; i += 8)
            Wtl[(size_t)(n0 + ty + i) * D + k0 + tx] = (_Float16)tb[tx][ty + i];
    }
}

// ---------------------------------------------------------------------------
// Merged scan + csr_fill (r10's scan_fill — correct there; cheap single-
// producer flag). Block 0 scans; blocks 1..625 spin then fill. All 626
// co-resident -> deadlock-free.
// ---------------------------------------------------------------------------
__global__ __launch_bounds__(256) void scan_fill(
    const int* __restrict__ in_deg, const int* __restrict__ out_deg,
    int* __restrict__ off, int* __restrict__ cursor,
    float* __restrict__ src_norm, float* __restrict__ dst_norm,
    const int* __restrict__ src, const int* __restrict__ dst,
    int* __restrict__ csr_src, int* flag) {
    if (blockIdx.x == 0) {
        __shared__ int lsum[256];
        int t = threadIdx.x;
        const int chunk = (N + 255) / 256;  // 40
        int start = t * chunk;
        int end = start + chunk; if (end > N) end = N;
        int s = 0;
        for (int i = start; i < end; ++i) s += in_deg[i];
        lsum[t] = s;
        __syncthreads();
        for (int d = 1; d < 256; d <<= 1) {
            int v = (t >= d) ? lsum[t - d] : 0;
            __syncthreads();
            lsum[t] += v;
            __syncthreads();
        }
        int excl = (t == 0) ? 0 : lsum[t - 1];
        for (int i = start; i < end; ++i) {
            off[i] = excl;
            cursor[i] = excl;
            excl += in_deg[i];
            int od = out_deg[i]; if (od < 1) od = 1;
            int id = in_deg[i];  if (id < 1) id = 1;
            src_norm[i] = rsqrtf((float)od);
            dst_norm[i] = rsqrtf((float)id);
        }
        if (t == 255) off[N] = lsum[255];
        __syncthreads();
        if (t == 0)
            __hip_atomic_store(flag, 1, __ATOMIC_RELEASE, __HIP_MEMORY_SCOPE_AGENT);
    } else {
        if (threadIdx.x == 0) {
            while (!__hip_atomic_load(flag, __ATOMIC_RELAXED, __HIP_MEMORY_SCOPE_AGENT))
                __builtin_amdgcn_s_sleep(8);
            (void)__hip_atomic_load(flag, __ATOMIC_ACQUIRE, __HIP_MEMORY_SCOPE_AGENT);
        }
        __syncthreads();
        __builtin_amdgcn_fence(__ATOMIC_ACQUIRE, "agent");
        int e = (blockIdx.x - 1) * 256 + threadIdx.x;
        if (e < E) {
            int d_ = dst[e];
            int pos = atomicAdd(&cursor[d_], 1);
            csr_src[pos] = src[e];
        }
    }
}

// ---------------------------------------------------------------------------
// Fused BN + gather-aggregate (r7 champion, verbatim). One wave per node,
// 4x edge unroll. ~36 µs/layer = L2/L3 random-gather bandwidth floor.
// ---------------------------------------------------------------------------
__global__ __launch_bounds__(256) void aggregate_bn(
    const _Float16* __restrict__ x, const int* __restrict__ off,
    const int* __restrict__ csr_src, const float* __restrict__ src_norm,
    const float* __restrict__ dst_norm, const float* __restrict__ stats,
    const float* __restrict__ gamma, const float* __restrict__ beta,
    _Float16* __restrict__ agg) {
    int wid = (blockIdx.x * 256 + threadIdx.x) >> 6;
    if (wid >= N) return;
    int lane = threadIdx.x & 63;
    int c0 = lane * 8;

    float scale[8], shift[8];
    const float invN = 1.0f / (float)N;
    for (int i = 0; i < 8; ++i) {
        int c = c0 + i;
        float mu = stats[c] * invN;
        float var = stats[D + c] * invN - mu * mu;
        float sc = gamma[c] * rsqrtf(var + EPS);
        scale[i] = sc;
        shift[i] = beta[c] - mu * sc;
    }

    int e0 = off[wid], e1 = off[wid + 1];
    float a[8] = {}, a2[8] = {};
    float t = 0.f;
    int e = e0;
    for (; e + 4 <= e1; e += 4) {
        int s0 = csr_src[e];
        int s1 = csr_src[e + 1];
        int s2 = csr_src[e + 2];
        int s3 = csr_src[e + 3];
        float n0 = src_norm[s0];
        float n1 = src_norm[s1];
        float n2 = src_norm[s2];
        float n3 = src_norm[s3];
        half8 v0 = *(const half8*)(x + (size_t)s0 * D + c0);
        half8 v1 = *(const half8*)(x + (size_t)s1 * D + c0);
        half8 v2 = *(const half8*)(x + (size_t)s2 * D + c0);
        half8 v3 = *(const half8*)(x + (size_t)s3 * D + c0);
        t += (n0 + n1) + (n2 + n3);
        for (int k = 0; k < 8; ++k) {
            a[k]  += (float)v0[k] * n0;
            a2[k] += (float)v1[k] * n1;
            a[k]  += (float)v2[k] * n2;
            a2[k] += (float)v3[k] * n3;
        }
    }
    for (; e < e1; ++e) {
        int s0 = csr_src[e];
        float n0 = src_norm[s0];
        half8 v0 = *(const half8*)(x + (size_t)s0 * D + c0);
        t += n0;
        for (int k = 0; k < 8; ++k) a[k] += (float)v0[k] * n0;
    }
    float dn = dst_norm[wid];
    half8 o;
    for (int i = 0; i < 8; ++i)
        o[i] = (_Float16)(dn * (scale[i] * (a[i] + a2[i]) + shift[i] * t));
    *(half8*)(agg + (size_t)wid * D + c0) = o;
}

// ---------------------------------------------------------------------------
// C = relu(A @ W + bias) via f16 MFMA with global_load_lds staging.
// A: M x 512 f16 row-major.  Bt[n][k] = W[k][n] f16.
// Tile 64(M) x 128(N), BK=32 -> 157x4 = 628 blocks (2.4/CU vs 1.2 at 128-row
// tiles; same total A/B traffic, half the acc VGPRs -> higher occupancy).
// Wave computes 32x64 (2x4 tiles of mfma_f32_16x16x32_f16).
// ---------------------------------------------------------------------------
template <typename OutT, bool STATS>
__global__ __launch_bounds__(256) void mm_f16_relu(
    const _Float16* __restrict__ A, const _Float16* __restrict__ Bt,
    const float* __restrict__ bias, OutT* __restrict__ C, int M,
    float* __restrict__ stats) {
    __shared__ __align__(16) _Float16 As[64 * 32];
    __shared__ __align__(16) _Float16 Bs[128 * 32];
    const int tid  = threadIdx.x;
    const int wave = tid >> 6;
    const int lane = tid & 63;
    const int quad = lane >> 4;
    const int l16  = lane & 15;
    const int row0 = blockIdx.x * 64;
    const int col0 = blockIdx.y * 128;
    const int wm = (wave & 1) * 32;
    const int wn = (wave >> 1) * 64;
    const int sr = lane >> 2;        // 16 rows per glds16 slab
    const int sc = (lane & 3) * 8;   // 4 lanes x 8 f16 = 32-k row

    // staging: wave w loads A rows [w*16, w*16+16) (1 slab) and B rows
    // [w*32, w*32+32) (2 slabs). Per-lane global ptr, wave-uniform LDS base.
    int ar = row0 + wave * 16 + sr;
    if (ar >= M) ar = M - 1;
    const _Float16* gA  = A + (size_t)ar * D + sc;
    const _Float16* gB0 = Bt + (size_t)(col0 + wave * 32 + sr) * D + sc;
    const _Float16* gB1 = Bt + (size_t)(col0 + wave * 32 + 16 + sr) * D + sc;
    _Float16* lA  = As + (wave * 16) * 32;
    _Float16* lB0 = Bs + (wave * 32) * 32;
    _Float16* lB1 = Bs + (wave * 32 + 16) * 32;

    floatx4 acc[2][4] = {};

    for (int k0 = 0; k0 < D; k0 += 32) {
        __syncthreads();
        glds16(gA + k0, lA);
        glds16(gB0 + k0, lB0);
        glds16(gB1 + k0, lB1);
        __syncthreads();  // compiler inserts vmcnt(0) drain here
        half8 af[2], bf[4];
        for (int i = 0; i < 2; ++i)
            af[i] = *(const half8*)(As + (wm + i * 16 + l16) * 32 + quad * 8);
        for (int j = 0; j < 4; ++j)
            bf[j] = *(const half8*)(Bs + (wn + j * 16 + l16) * 32 + quad * 8);
        for (int i = 0; i < 2; ++i)
            for (int j = 0; j < 4; ++j)
                acc[i][j] = __builtin_amdgcn_mfma_f32_16x16x32_f16(
                    af[i], bf[j], acc[i][j], 0, 0, 0);
    }

    // epilogue: C/D layout col = lane&15, row = quad*4 + reg
    float s[4] = {}, q[4] = {};
    for (int i = 0; i < 2; ++i) {
        for (int r = 0; r < 4; ++r) {
            int row = row0 + wm + i * 16 + quad * 4 + r;
            bool valid = row < M;
            for (int j = 0; j < 4; ++j) {
                int col = col0 + wn + j * 16 + l16;
                float v = acc[i][j][r] + bias[col];
                v = v > 0.f ? v : 0.f;
                if (valid) {
                    C[(size_t)row * D + col] = (OutT)v;
                    if (STATS) { s[j] += v; q[j] += v * v; }
                }
            }
        }
    }
    if (STATS) {
        for (int j = 0; j < 4; ++j) {
            float sv = s[j], qv = q[j];
            sv += __shfl_xor(sv, 16); sv += __shfl_xor(sv, 32);
            qv += __shfl_xor(qv, 16); qv += __shfl_xor(qv, 32);
            if (quad == 0) {
                int col = col0 + wn + j * 16 + l16;
                atomicAdd(&stats[col], sv);
                atomicAdd(&stats[D + col], qv);
            }
        }
    }
}

// ---------------------------------------------------------------------------
extern "C" void kernel_launch(void* const* d_in, const int* in_sizes, int n_in,
                              void* d_out, int out_size, void* d_ws, size_t ws_size,
                              hipStream_t stream) {
    const float* x_in  = (const float*)d_in[0];
    const int*   src   = (const int*)d_in[1];
    const int*   dst   = (const int*)d_in[2];
    const float* gamma = (const float*)d_in[3];
    const float* beta  = (const float*)d_in[4];
    const float* W     = (const float*)d_in[5];
    const float* b     = (const float*)d_in[6];
    float* out = (float*)d_out;

    // workspace carve-up (16B-aligned segments first)
    char* p = (char*)d_ws;
    _Float16* x16 = (_Float16*)p;  p += (size_t)N * D * 2;       // 10.24 MB
    _Float16* agg = (_Float16*)p;  p += (size_t)N * D * 2;       // 10.24 MB
    _Float16* Wt  = (_Float16*)p;  p += (size_t)L * D * D * 2;   // 1.57 MB
    float* src_norm = (float*)p;   p += (size_t)N * 4;
    float* dst_norm = (float*)p;   p += (size_t)N * 4;
    // contiguous zero-init region: out_deg, in_deg, stats0..2, flag
    int* out_deg   = (int*)p;      p += (size_t)N * 4;
    int* in_deg    = (int*)p;      p += (size_t)N * 4;
    float* stats0  = (float*)p;    p += 2 * D * 4;
    float* stats1  = (float*)p;    p += 2 * D * 4;
    float* stats2  = (float*)p;    p += 2 * D * 4;
    int* flag      = (int*)p;      p += 16 * 4;
    size_t zero_bytes = (size_t)((char*)p - (char*)out_deg);
    int* csr_off   = (int*)p;      p += (size_t)(N + 1) * 4;
    int* cursor    = (int*)p;      p += (size_t)N * 4;
    int* csr_src   = (int*)p;      p += (size_t)E * 4;

    float* stats_in[3] = {stats0, stats1, stats2};

    // --- setup: memset + 2 dispatches ---
    hipMemsetAsync(out_deg, 0, zero_bytes, stream);
    mega_setup<<<MEGA_BLOCKS, 256, 0, stream>>>(src, dst, x_in, W,
                                                out_deg, in_deg, x16, stats0, Wt);
    scan_fill<<<1 + DEG_BLOCKS, 256, 0, stream>>>(in_deg, out_deg, csr_off, cursor,
                                                  src_norm, dst_norm, src, dst,
                                                  csr_src, flag);

    dim3 mm_grid((N + 63) / 64, D / 128);   // 157 x 4 = 628 blocks
    const int agg_blocks = (N + 3) / 4;     // 4 waves per 256-thread block

    for (int l = 0; l < L; ++l) {
        const float* gl  = gamma + (size_t)l * D;
        const float* bl  = beta + (size_t)l * D;
        const _Float16* Wl = Wt + (size_t)l * D * D;
        const float* bil = b + (size_t)l * D;

        aggregate_bn<<<agg_blocks, 256, 0, stream>>>(
            x16, csr_off, csr_src, src_norm, dst_norm, stats_in[l], gl, bl, agg);
        if (l == L - 1) {
            mm_f16_relu<float, false><<<mm_grid, 256, 0, stream>>>(
                agg, Wl, bil, out, N, nullptr);
        } else {
            mm_f16_relu<_Float16, true><<<mm_grid, 256, 0, stream>>>(
                agg, Wl, bil, x16, N, stats_in[l + 1]);
        }
    }
}